// Round 4
// baseline (5051.335 us; speedup 1.0000x reference)
//
#include <hip/hip_runtime.h>

#define B_ 64
#define T_ 512
#define I_ 512
#define H_ 1024
#define PLANE 65536   // uints per h plane (B_*H_), fragment-major packed hi|lo
#define FPAD 16       // pad flags/counters to 64 B lines
#define NCNT 16       // aggregated sync counters
#define G_ 64

typedef __attribute__((ext_vector_type(8))) short bf16x8;
typedef __attribute__((ext_vector_type(4))) float f32x4;

static __device__ __forceinline__ short f2bf(float f) {
  unsigned u = __float_as_uint(f);
  unsigned r = (u + 0x7fffu + ((u >> 16) & 1u)) >> 16;  // RNE
  return (short)(unsigned short)r;
}
static __device__ __forceinline__ float bf2f(short s) {
  return __uint_as_float(((unsigned)(unsigned short)s) << 16);
}
static __device__ __forceinline__ bf16x8 pack8(float4 u, float4 v) {
  bf16x8 r;
  r[0] = f2bf(u.x); r[1] = f2bf(u.y); r[2] = f2bf(u.z); r[3] = f2bf(u.w);
  r[4] = f2bf(v.x); r[5] = f2bf(v.y); r[6] = f2bf(v.z); r[7] = f2bf(v.w);
  return r;
}

// ---------------------------------------------------------------------------
// Kernel 1 (unchanged): pre = x @ Wi^T + bi + bh, in-place into d_out.
// ---------------------------------------------------------------------------
#define PBK 32
#define PLDA 40

__global__ __launch_bounds__(256) void proj_gemm(
    const float* __restrict__ x, const float* __restrict__ Wi,
    const float* __restrict__ bi, const float* __restrict__ bh,
    float* __restrict__ out) {
  __shared__ short As[128 * PLDA];
  __shared__ short Bs[128 * PLDA];
  const int tid = threadIdx.x;
  const int m0 = (blockIdx.x >> 3) * 128;
  const int n0 = (blockIdx.x & 7) * 128;
  const int wave = tid >> 6, lane = tid & 63;
  const int wm = (wave & 1) * 64, wn = (wave >> 1) * 64;
  const int lm = lane & 15, lq = lane >> 4;

  f32x4 acc[4][4];
#pragma unroll
  for (int i = 0; i < 4; ++i)
#pragma unroll
    for (int j = 0; j < 4; ++j) {
      f32x4 z = {0.f, 0.f, 0.f, 0.f};
      acc[i][j] = z;
    }

  const int lrow = tid >> 1;
  const int lcol = (tid & 1) * 16;
  const float* xp = x + (size_t)(m0 + lrow) * I_ + lcol;
  const float* wp = Wi + (size_t)(n0 + lrow) * I_ + lcol;

  for (int k0 = 0; k0 < I_; k0 += PBK) {
    float4 a0 = *(const float4*)(xp + k0);
    float4 a1 = *(const float4*)(xp + k0 + 4);
    float4 a2 = *(const float4*)(xp + k0 + 8);
    float4 a3 = *(const float4*)(xp + k0 + 12);
    float4 b0 = *(const float4*)(wp + k0);
    float4 b1 = *(const float4*)(wp + k0 + 4);
    float4 b2 = *(const float4*)(wp + k0 + 8);
    float4 b3 = *(const float4*)(wp + k0 + 12);
    __syncthreads();
    *(bf16x8*)&As[lrow * PLDA + lcol] = pack8(a0, a1);
    *(bf16x8*)&As[lrow * PLDA + lcol + 8] = pack8(a2, a3);
    *(bf16x8*)&Bs[lrow * PLDA + lcol] = pack8(b0, b1);
    *(bf16x8*)&Bs[lrow * PLDA + lcol + 8] = pack8(b2, b3);
    __syncthreads();

    bf16x8 af[4], bfr[4];
#pragma unroll
    for (int i = 0; i < 4; ++i)
      af[i] = *(const bf16x8*)&As[(wm + i * 16 + lm) * PLDA + lq * 8];
#pragma unroll
    for (int j = 0; j < 4; ++j)
      bfr[j] = *(const bf16x8*)&Bs[(wn + j * 16 + lm) * PLDA + lq * 8];
#pragma unroll
    for (int i = 0; i < 4; ++i)
#pragma unroll
      for (int j = 0; j < 4; ++j)
        acc[i][j] = __builtin_amdgcn_mfma_f32_16x16x32_bf16(af[i], bfr[j],
                                                            acc[i][j], 0, 0, 0);
  }

  const int rb = m0 + wm + lq * 4;
  const int cb = n0 + wn + lm;
#pragma unroll
  for (int j = 0; j < 4; ++j) {
    const int n = cb + j * 16;
    const float bias = bi[n] + bh[n];
#pragma unroll
    for (int i = 0; i < 4; ++i) {
      const int m = rb + i * 16;
#pragma unroll
      for (int r = 0; r < 4; ++r)
        out[(size_t)(m + r) * H_ + n] = acc[i][j][r] + bias;
    }
  }
}

// ---------------------------------------------------------------------------
// Agent-scope (L3-coherent, L2-bypassing) helpers.
// ---------------------------------------------------------------------------
static __device__ __forceinline__ unsigned long long ld_a8(const void* p) {
  return __hip_atomic_load((const unsigned long long*)p, __ATOMIC_RELAXED,
                           __HIP_MEMORY_SCOPE_AGENT);
}
static __device__ __forceinline__ void st_a4(unsigned* p, unsigned v) {
  __hip_atomic_store(p, v, __ATOMIC_RELAXED, __HIP_MEMORY_SCOPE_AGENT);
}
static __device__ __forceinline__ int ld_flag(const int* p) {
  return __hip_atomic_load(p, __ATOMIC_RELAXED, __HIP_MEMORY_SCOPE_AGENT);
}

// ---------------------------------------------------------------------------
// Kernel 2: persistent recurrence, fragment-major h exchange, aggregated-
// counter sync.
//
// h plane layout (uint = bf16 hi | lo<<16): element (b,n) with
//   wv=b>>4, lm=b&15, kb=n>>5, lq=(n>>3)&3, j=n&7, c=j>>1, L=lq*16+lm:
//   U(b,n) = (kb*4+wv)*512 + c*128 + L*2 + (j&1)
// => consumer wave wv at K-block kb issues 4 ld_a8 at byte offsets
//    (kb*4+wv)*2048 + c*512 + lane*8  -- 64 lanes x 8 B fully dense.
//
// Sync: 16 monotone agent-scope counters. Wave w (global id 4g+wv) does
// atomicAdd(&cnt[(4g+wv)&15],1) after its h_s stores drained (vmcnt(0)) --
// so cnt[j] >= 16*s proves: every wave stored h_s to L3 AND every wave's
// step-s A-loads (of plane (s-1)&1) retired. Step-s start condition:
// all 16 counters >= 16*(s-1). Poll cost: 16 lines/wave-round (lanes 0-15),
// ~4000x less fabric traffic than R3's 256-line wait-all.
// ---------------------------------------------------------------------------
__global__ __launch_bounds__(256, 1) void rnn_rec(
    const float* __restrict__ Wh, float* __restrict__ out,
    unsigned* __restrict__ planes, int* __restrict__ flags,
    int* __restrict__ cnt) {
  __shared__ short BhiS[2048 * 8];  // 32 KB, B-frag order
  __shared__ short BloS[2048 * 8];  // 32 KB
  const int tid = threadIdx.x;
  const int g = blockIdx.x;
  const int n0 = g * 16;
  const int wv = tid >> 6;   // 0..3
  const int lane = tid & 63;
  const int lm = lane & 15, lq = lane >> 4;

  // --- stage Wh hi/lo into LDS in exact B-frag order ---
  for (int idx = tid; idx < 2048; idx += 256) {
    const int kb = idx >> 6, l = idx & 63;
    const int n = n0 + (l & 15);
    const int k = kb * 32 + (l >> 4) * 8;
    const float* p = Wh + (size_t)n * H_ + k;
    float4 w0 = *(const float4*)p;
    float4 w1 = *(const float4*)(p + 4);
    float wf[8] = {w0.x, w0.y, w0.z, w0.w, w1.x, w1.y, w1.z, w1.w};
#pragma unroll
    for (int j = 0; j < 8; ++j) {
      const short h = f2bf(wf[j]);
      BhiS[idx * 8 + j] = h;
      BloS[idx * 8 + j] = f2bf(wf[j] - bf2f(h));
    }
  }

  // --- producer-side address constants (thread owns (b,np), b=wv*16+lq*4+r) ---
  const int np = n0 + lm;
  const int kbp = np >> 5, lqp = (np >> 3) & 3, jp = np & 7;
  const int Ubase = (kbp * 4 + wv) * 512 + (jp >> 1) * 128 + lqp * 32 + (jp & 1);

  // --- startup: zero h_0 (plane 0) own cols; WGs 0..15 zero one counter ---
#pragma unroll
  for (int r = 0; r < 4; ++r) st_a4(&planes[Ubase + (lq * 4 + r) * 2], 0u);
  if (g < NCNT && tid == 0)
    __hip_atomic_store(&cnt[g * FPAD], 0, __ATOMIC_RELAXED,
                       __HIP_MEMORY_SCOPE_AGENT);
  asm volatile("s_waitcnt vmcnt(0)" ::: "memory");
  __syncthreads();  // whole WG's zeros drained
  if (tid == 0)
    __hip_atomic_store(&flags[g * FPAD], 1, __ATOMIC_RELAXED,
                       __HIP_MEMORY_SCOPE_AGENT);
  // init barrier: every wave polls all 64 WG flags (>=1 works on 0xAA poison)
  for (;;) {
    const int f = ld_flag(&flags[lane * FPAD]);
    if (__all(f >= 1)) break;
  }

  float* outH = out + (size_t)B_ * T_ * H_;
  const f32x4 z = {0.f, 0.f, 0.f, 0.f};
  const int sidx = ((g << 2) | wv) & (NCNT - 1);  // this wave's counter

  for (int s = 1; s <= T_; ++s) {
    const int t = s - 1;
    // prefetch pre values (independent of sync; overlaps the poll)
    size_t oidx[4];
    float pre[4];
#pragma unroll
    for (int r = 0; r < 4; ++r) {
      const int b = wv * 16 + lq * 4 + r;
      oidx[r] = (size_t)b * (T_ * H_) + (size_t)t * H_ + np;
      pre[r] = out[oidx[r]];
    }

    // wait: all 16 counters >= 16*(s-1); lanes 0..15 poll one line each
    const int need = NCNT * (s - 1);
    for (;;) {
      int c = need;
      if (lane < NCNT) c = ld_flag(&cnt[lane * FPAD]);
      if (__all(c >= need)) break;
    }

    const char* src = (const char*)(planes + (size_t)((s - 1) & 1) * PLANE);
    unsigned* dst = planes + (size_t)(s & 1) * PLANE;

    // 16-deep dense A-load pipeline: block kb, chunk c at byte
    //   (kb*4+wv)*2048 + c*512 + lane*8
    unsigned long long pq[16][4];
#pragma unroll
    for (int k2 = 0; k2 < 16; ++k2) {
      const char* p = src + ((size_t)(k2 * 4 + wv) * 2048) + lane * 8;
      pq[k2][0] = ld_a8(p);
      pq[k2][1] = ld_a8(p + 512);
      pq[k2][2] = ld_a8(p + 1024);
      pq[k2][3] = ld_a8(p + 1536);
    }

    f32x4 c0 = z, c1 = z, c2 = z;
#pragma unroll
    for (int kb = 0; kb < 32; ++kb) {
      const int sl = kb & 15;
      bf16x8 ah, al;
#pragma unroll
      for (int c = 0; c < 4; ++c) {
        const unsigned u0 = (unsigned)pq[sl][c];
        const unsigned u1 = (unsigned)(pq[sl][c] >> 32);
        ah[2 * c] = (short)(u0 & 0xffffu);
        al[2 * c] = (short)(u0 >> 16);
        ah[2 * c + 1] = (short)(u1 & 0xffffu);
        al[2 * c + 1] = (short)(u1 >> 16);
      }
      const bf16x8 bh = *(const bf16x8*)&BhiS[(kb * 64 + lane) * 8];
      const bf16x8 bl = *(const bf16x8*)&BloS[(kb * 64 + lane) * 8];
      c0 = __builtin_amdgcn_mfma_f32_16x16x32_bf16(ah, bh, c0, 0, 0, 0);
      c1 = __builtin_amdgcn_mfma_f32_16x16x32_bf16(ah, bl, c1, 0, 0, 0);
      c2 = __builtin_amdgcn_mfma_f32_16x16x32_bf16(al, bh, c2, 0, 0, 0);
      if (kb + 16 < 32) {
        const char* p = src + ((size_t)((kb + 16) * 4 + wv) * 2048) + lane * 8;
        pq[sl][0] = ld_a8(p);
        pq[sl][1] = ld_a8(p + 512);
        pq[sl][2] = ld_a8(p + 1024);
        pq[sl][3] = ld_a8(p + 1536);
      }
    }
    const f32x4 rs = c0 + c1 + c2;

    // epilogue: h-plane stores FIRST, drain, signal; out-writes after
    float v[4];
#pragma unroll
    for (int r = 0; r < 4; ++r) {
      float vv = pre[r] + rs[r];
      vv = vv > 0.f ? vv : 0.f;
      v[r] = vv;
      const short hv = f2bf(vv);
      const short lv = f2bf(vv - bf2f(hv));
      st_a4(&dst[Ubase + (lq * 4 + r) * 2],
            (unsigned)(unsigned short)hv | ((unsigned)(unsigned short)lv << 16));
    }
    asm volatile("s_waitcnt vmcnt(0)" ::: "memory");  // h slice at L3
    if (lane == 0)
      __hip_atomic_fetch_add(&cnt[sidx * FPAD], 1, __ATOMIC_RELAXED,
                             __HIP_MEMORY_SCOPE_AGENT);
#pragma unroll
    for (int r = 0; r < 4; ++r) {
      out[oidx[r]] = v[r];
      if (s == T_) outH[(size_t)(wv * 16 + lq * 4 + r) * H_ + np] = v[r];
    }
  }
}

// ---------------------------------------------------------------------------
extern "C" void kernel_launch(void* const* d_in, const int* in_sizes, int n_in,
                              void* d_out, int out_size, void* d_ws,
                              size_t ws_size, hipStream_t stream) {
  const float* x = (const float*)d_in[0];   // [B,T,I]
  const float* Wi = (const float*)d_in[1];  // [H,I]
  const float* bi = (const float*)d_in[2];  // [H]
  const float* Wh = (const float*)d_in[3];  // [H,H]
  const float* bh = (const float*)d_in[4];  // [H]
  float* out = (float*)d_out;

  int* flags = (int*)d_ws;                              // 64 x 64 B = 4 KB
  int* cnt = flags + G_ * FPAD;                         // 16 x 64 B = 1 KB
  unsigned* planes = (unsigned*)((char*)d_ws + (G_ + NCNT) * FPAD * 4);

  proj_gemm<<<2048, 256, 0, stream>>>(x, Wi, bi, bh, out);
  rnn_rec<<<G_, 256, 0, stream>>>(Wh, out, planes, flags, cnt);
}

// Round 5
// 3315.031 us; speedup vs baseline: 1.5238x; 1.5238x over previous
//
#include <hip/hip_runtime.h>

#define B_ 64
#define T_ 512
#define I_ 512
#define H_ 1024
#define PLANE 65536   // uints per h plane (B_*H_), fragment-major packed hi|lo
#define FPAD 16       // pad flags to 64 B lines
#define G_ 64

typedef __attribute__((ext_vector_type(8))) short bf16x8;
typedef __attribute__((ext_vector_type(4))) float f32x4;

static __device__ __forceinline__ short f2bf(float f) {
  unsigned u = __float_as_uint(f);
  unsigned r = (u + 0x7fffu + ((u >> 16) & 1u)) >> 16;  // RNE
  return (short)(unsigned short)r;
}
static __device__ __forceinline__ float bf2f(short s) {
  return __uint_as_float(((unsigned)(unsigned short)s) << 16);
}
static __device__ __forceinline__ bf16x8 pack8(float4 u, float4 v) {
  bf16x8 r;
  r[0] = f2bf(u.x); r[1] = f2bf(u.y); r[2] = f2bf(u.z); r[3] = f2bf(u.w);
  r[4] = f2bf(v.x); r[5] = f2bf(v.y); r[6] = f2bf(v.z); r[7] = f2bf(v.w);
  return r;
}

// ---------------------------------------------------------------------------
// Kernel 1 (unchanged): pre = x @ Wi^T + bi + bh, in-place into d_out.
// ---------------------------------------------------------------------------
#define PBK 32
#define PLDA 40

__global__ __launch_bounds__(256) void proj_gemm(
    const float* __restrict__ x, const float* __restrict__ Wi,
    const float* __restrict__ bi, const float* __restrict__ bh,
    float* __restrict__ out) {
  __shared__ short As[128 * PLDA];
  __shared__ short Bs[128 * PLDA];
  const int tid = threadIdx.x;
  const int m0 = (blockIdx.x >> 3) * 128;
  const int n0 = (blockIdx.x & 7) * 128;
  const int wave = tid >> 6, lane = tid & 63;
  const int wm = (wave & 1) * 64, wn = (wave >> 1) * 64;
  const int lm = lane & 15, lq = lane >> 4;

  f32x4 acc[4][4];
#pragma unroll
  for (int i = 0; i < 4; ++i)
#pragma unroll
    for (int j = 0; j < 4; ++j) {
      f32x4 z = {0.f, 0.f, 0.f, 0.f};
      acc[i][j] = z;
    }

  const int lrow = tid >> 1;
  const int lcol = (tid & 1) * 16;
  const float* xp = x + (size_t)(m0 + lrow) * I_ + lcol;
  const float* wp = Wi + (size_t)(n0 + lrow) * I_ + lcol;

  for (int k0 = 0; k0 < I_; k0 += PBK) {
    float4 a0 = *(const float4*)(xp + k0);
    float4 a1 = *(const float4*)(xp + k0 + 4);
    float4 a2 = *(const float4*)(xp + k0 + 8);
    float4 a3 = *(const float4*)(xp + k0 + 12);
    float4 b0 = *(const float4*)(wp + k0);
    float4 b1 = *(const float4*)(wp + k0 + 4);
    float4 b2 = *(const float4*)(wp + k0 + 8);
    float4 b3 = *(const float4*)(wp + k0 + 12);
    __syncthreads();
    *(bf16x8*)&As[lrow * PLDA + lcol] = pack8(a0, a1);
    *(bf16x8*)&As[lrow * PLDA + lcol + 8] = pack8(a2, a3);
    *(bf16x8*)&Bs[lrow * PLDA + lcol] = pack8(b0, b1);
    *(bf16x8*)&Bs[lrow * PLDA + lcol + 8] = pack8(b2, b3);
    __syncthreads();

    bf16x8 af[4], bfr[4];
#pragma unroll
    for (int i = 0; i < 4; ++i)
      af[i] = *(const bf16x8*)&As[(wm + i * 16 + lm) * PLDA + lq * 8];
#pragma unroll
    for (int j = 0; j < 4; ++j)
      bfr[j] = *(const bf16x8*)&Bs[(wn + j * 16 + lm) * PLDA + lq * 8];
#pragma unroll
    for (int i = 0; i < 4; ++i)
#pragma unroll
      for (int j = 0; j < 4; ++j)
        acc[i][j] = __builtin_amdgcn_mfma_f32_16x16x32_bf16(af[i], bfr[j],
                                                            acc[i][j], 0, 0, 0);
  }

  const int rb = m0 + wm + lq * 4;
  const int cb = n0 + wn + lm;
#pragma unroll
  for (int j = 0; j < 4; ++j) {
    const int n = cb + j * 16;
    const float bias = bi[n] + bh[n];
#pragma unroll
    for (int i = 0; i < 4; ++i) {
      const int m = rb + i * 16;
#pragma unroll
      for (int r = 0; r < 4; ++r)
        out[(size_t)(m + r) * H_ + n] = acc[i][j][r] + bias;
    }
  }
}

// ---------------------------------------------------------------------------
// Agent-scope (L3-coherent, L2-bypassing) helpers.
// ---------------------------------------------------------------------------
static __device__ __forceinline__ unsigned long long ld_a8(const void* p) {
  return __hip_atomic_load((const unsigned long long*)p, __ATOMIC_RELAXED,
                           __HIP_MEMORY_SCOPE_AGENT);
}
static __device__ __forceinline__ void st_a4(unsigned* p, unsigned v) {
  __hip_atomic_store(p, v, __ATOMIC_RELAXED, __HIP_MEMORY_SCOPE_AGENT);
}
static __device__ __forceinline__ int ld_flag(const int* p) {
  return __hip_atomic_load(p, __ATOMIC_RELAXED, __HIP_MEMORY_SCOPE_AGENT);
}

// ---------------------------------------------------------------------------
// Kernel 2: persistent recurrence, fragment-major h exchange, per-WG flags,
// staggered K-walk.
//
// h plane layout (uint = bf16 hi | lo<<16): element (b,n) with
//   wv=b>>4, lm=b&15, kb=n>>5, lq=(n>>3)&3, j=n&7, c=j>>1, L=lq*16+lm:
//   U(b,n) = (kb*4+wv)*512 + c*128 + L*2 + (j&1)
// => consumer wave wv at K-block kb issues 4 ld_a8 at byte offsets
//    (kb*4+wv)*2048 + c*512 + lane*8  -- 64 lanes x 8 B fully dense.
//
// kb STAGGER: WG g walks kb = (g+i) & 31. Without stagger all 64 WGs read
// the same 64 B lines in lockstep (64-way L3 line collision -> ~2 TB/s
// effective in R3/R4). With stagger, max 2 WGs (g, g+32) share a sequence.
//
// Sync: 64 per-WG flags. Producer: h-stores -> per-wave vmcnt(0) ->
// __syncthreads -> tid0 stores flag[g]=s. Consumer: one sc1 load per poll
// round (lane l polls flag[l]) + s_sleep backoff. flag[g]>=s proves WG g's
// h_s is at L3 AND its plane-((s-1)&1) reads retired -> ping-pong safe.
// ---------------------------------------------------------------------------
__global__ __launch_bounds__(256, 1) void rnn_rec(
    const float* __restrict__ Wh, float* __restrict__ out,
    unsigned* __restrict__ planes, int* __restrict__ flags) {
  __shared__ short BhiS[2048 * 8];  // 32 KB, B-frag order
  __shared__ short BloS[2048 * 8];  // 32 KB
  const int tid = threadIdx.x;
  const int g = blockIdx.x;
  const int n0 = g * 16;
  const int wv = tid >> 6;   // 0..3
  const int lane = tid & 63;
  const int lm = lane & 15, lq = lane >> 4;
  const int kb0 = g & 31;    // staggered K start

  // --- stage Wh hi/lo into LDS in exact B-frag order ---
  for (int idx = tid; idx < 2048; idx += 256) {
    const int kb = idx >> 6, l = idx & 63;
    const int n = n0 + (l & 15);
    const int k = kb * 32 + (l >> 4) * 8;
    const float* p = Wh + (size_t)n * H_ + k;
    float4 w0 = *(const float4*)p;
    float4 w1 = *(const float4*)(p + 4);
    float wf[8] = {w0.x, w0.y, w0.z, w0.w, w1.x, w1.y, w1.z, w1.w};
#pragma unroll
    for (int j = 0; j < 8; ++j) {
      const short h = f2bf(wf[j]);
      BhiS[idx * 8 + j] = h;
      BloS[idx * 8 + j] = f2bf(wf[j] - bf2f(h));
    }
  }

  // --- producer-side address constants (thread owns (b,np), b=wv*16+lq*4+r) ---
  const int np = n0 + lm;
  const int kbp = np >> 5, lqp = (np >> 3) & 3, jp = np & 7;
  const int Ubase = (kbp * 4 + wv) * 512 + (jp >> 1) * 128 + lqp * 32 + (jp & 1);

  // --- startup: zero h_0 (plane 0) own cols; flag[g]=0; wait all >= 0 ---
#pragma unroll
  for (int r = 0; r < 4; ++r) st_a4(&planes[Ubase + (lq * 4 + r) * 2], 0u);
  asm volatile("s_waitcnt vmcnt(0)" ::: "memory");
  __syncthreads();  // whole WG's zeros + LDS staging done
  if (tid == 0)
    __hip_atomic_store(&flags[g * FPAD], 0, __ATOMIC_RELAXED,
                       __HIP_MEMORY_SCOPE_AGENT);
  // init barrier: 0xAA poison is negative, so >=0 means "flag written"
  for (;;) {
    const int f = ld_flag(&flags[lane * FPAD]);
    if (__all(f >= 0)) break;
    __builtin_amdgcn_s_sleep(1);
  }

  float* outH = out + (size_t)B_ * T_ * H_;
  const f32x4 z = {0.f, 0.f, 0.f, 0.f};

  for (int s = 1; s <= T_; ++s) {
    const int t = s - 1;
    // prefetch pre values (independent of sync; overlaps the poll)
    size_t oidx[4];
    float pre[4];
#pragma unroll
    for (int r = 0; r < 4; ++r) {
      const int b = wv * 16 + lq * 4 + r;
      oidx[r] = (size_t)b * (T_ * H_) + (size_t)t * H_ + np;
      pre[r] = out[oidx[r]];
    }

    // wait: all 64 WG flags >= s-1; ONE sc1 load per round + sleep backoff
    const int need = s - 1;
    for (;;) {
      const int f = ld_flag(&flags[lane * FPAD]);
      if (__all(f >= need)) break;
      __builtin_amdgcn_s_sleep(1);
    }

    const char* src = (const char*)(planes + (size_t)((s - 1) & 1) * PLANE);
    unsigned* dst = planes + (size_t)(s & 1) * PLANE;

    // 16-deep dense A-load pipeline over staggered kb sequence (kb0+i)&31:
    // chunk c of block kb at byte (kb*4+wv)*2048 + c*512 + lane*8
    unsigned long long pq[16][4];
#pragma unroll
    for (int i = 0; i < 16; ++i) {
      const int km = (kb0 + i) & 31;
      const char* p = src + ((size_t)(km * 4 + wv) * 2048) + lane * 8;
      pq[i][0] = ld_a8(p);
      pq[i][1] = ld_a8(p + 512);
      pq[i][2] = ld_a8(p + 1024);
      pq[i][3] = ld_a8(p + 1536);
    }

    f32x4 c0 = z, c1 = z, c2 = z;
#pragma unroll
    for (int i = 0; i < 32; ++i) {
      const int km = (kb0 + i) & 31;
      const int sl = i & 15;
      bf16x8 ah, al;
#pragma unroll
      for (int c = 0; c < 4; ++c) {
        const unsigned u0 = (unsigned)pq[sl][c];
        const unsigned u1 = (unsigned)(pq[sl][c] >> 32);
        ah[2 * c] = (short)(u0 & 0xffffu);
        al[2 * c] = (short)(u0 >> 16);
        ah[2 * c + 1] = (short)(u1 & 0xffffu);
        al[2 * c + 1] = (short)(u1 >> 16);
      }
      const bf16x8 bh = *(const bf16x8*)&BhiS[(km * 64 + lane) * 8];
      const bf16x8 bl = *(const bf16x8*)&BloS[(km * 64 + lane) * 8];
      c0 = __builtin_amdgcn_mfma_f32_16x16x32_bf16(ah, bh, c0, 0, 0, 0);
      c1 = __builtin_amdgcn_mfma_f32_16x16x32_bf16(ah, bl, c1, 0, 0, 0);
      c2 = __builtin_amdgcn_mfma_f32_16x16x32_bf16(al, bh, c2, 0, 0, 0);
      if (i + 16 < 32) {
        const int kn = (kb0 + i + 16) & 31;
        const char* p = src + ((size_t)(kn * 4 + wv) * 2048) + lane * 8;
        pq[sl][0] = ld_a8(p);
        pq[sl][1] = ld_a8(p + 512);
        pq[sl][2] = ld_a8(p + 1024);
        pq[sl][3] = ld_a8(p + 1536);
      }
    }
    const f32x4 rs = c0 + c1 + c2;

    // epilogue: h-plane stores FIRST, per-wave drain, WG-convergence, signal
    float v[4];
#pragma unroll
    for (int r = 0; r < 4; ++r) {
      float vv = pre[r] + rs[r];
      vv = vv > 0.f ? vv : 0.f;
      v[r] = vv;
      const short hv = f2bf(vv);
      const short lv = f2bf(vv - bf2f(hv));
      st_a4(&dst[Ubase + (lq * 4 + r) * 2],
            (unsigned)(unsigned short)hv | ((unsigned)(unsigned short)lv << 16));
    }
    asm volatile("s_waitcnt vmcnt(0)" ::: "memory");  // this wave's h at L3
    __syncthreads();                                  // all 4 waves drained
    if (tid == 0)
      __hip_atomic_store(&flags[g * FPAD], s, __ATOMIC_RELAXED,
                         __HIP_MEMORY_SCOPE_AGENT);
    // out writes off the critical chain (WG-private, L2-cached)
#pragma unroll
    for (int r = 0; r < 4; ++r) {
      out[oidx[r]] = v[r];
      if (s == T_) outH[(size_t)(wv * 16 + lq * 4 + r) * H_ + np] = v[r];
    }
  }
}

// ---------------------------------------------------------------------------
extern "C" void kernel_launch(void* const* d_in, const int* in_sizes, int n_in,
                              void* d_out, int out_size, void* d_ws,
                              size_t ws_size, hipStream_t stream) {
  const float* x = (const float*)d_in[0];   // [B,T,I]
  const float* Wi = (const float*)d_in[1];  // [H,I]
  const float* bi = (const float*)d_in[2];  // [H]
  const float* Wh = (const float*)d_in[3];  // [H,H]
  const float* bh = (const float*)d_in[4];  // [H]
  float* out = (float*)d_out;

  int* flags = (int*)d_ws;  // 64 x 64 B = 4 KB
  unsigned* planes = (unsigned*)((char*)d_ws + G_ * FPAD * 4);  // 2 x 256 KB

  proj_gemm<<<2048, 256, 0, stream>>>(x, Wi, bi, bh, out);
  rnn_rec<<<G_, 256, 0, stream>>>(Wh, out, planes, flags);
}

// Round 6
// 3268.631 us; speedup vs baseline: 1.5454x; 1.0142x over previous
//
#include <hip/hip_runtime.h>

#define B_ 64
#define T_ 512
#define I_ 512
#define H_ 1024
#define PSH 65536     // shorts per plane (B_*H_); plane pair = hi+lo = 131072 shorts
#define FPAD 16       // pad flags to 64 B lines
#define G_ 64

typedef __attribute__((ext_vector_type(8))) short bf16x8;
typedef __attribute__((ext_vector_type(4))) float f32x4;

static __device__ __forceinline__ short f2bf(float f) {
  unsigned u = __float_as_uint(f);
  unsigned r = (u + 0x7fffu + ((u >> 16) & 1u)) >> 16;  // RNE
  return (short)(unsigned short)r;
}
static __device__ __forceinline__ float bf2f(short s) {
  return __uint_as_float(((unsigned)(unsigned short)s) << 16);
}
static __device__ __forceinline__ bf16x8 pack8(float4 u, float4 v) {
  bf16x8 r;
  r[0] = f2bf(u.x); r[1] = f2bf(u.y); r[2] = f2bf(u.z); r[3] = f2bf(u.w);
  r[4] = f2bf(v.x); r[5] = f2bf(v.y); r[6] = f2bf(v.z); r[7] = f2bf(v.w);
  return r;
}

// ---------------------------------------------------------------------------
// Kernel 1 (unchanged): pre = x @ Wi^T + bi + bh, in-place into d_out.
// ---------------------------------------------------------------------------
#define PBK 32
#define PLDA 40

__global__ __launch_bounds__(256) void proj_gemm(
    const float* __restrict__ x, const float* __restrict__ Wi,
    const float* __restrict__ bi, const float* __restrict__ bh,
    float* __restrict__ out) {
  __shared__ short As[128 * PLDA];
  __shared__ short Bs[128 * PLDA];
  const int tid = threadIdx.x;
  const int m0 = (blockIdx.x >> 3) * 128;
  const int n0 = (blockIdx.x & 7) * 128;
  const int wave = tid >> 6, lane = tid & 63;
  const int wm = (wave & 1) * 64, wn = (wave >> 1) * 64;
  const int lm = lane & 15, lq = lane >> 4;

  f32x4 acc[4][4];
#pragma unroll
  for (int i = 0; i < 4; ++i)
#pragma unroll
    for (int j = 0; j < 4; ++j) {
      f32x4 z = {0.f, 0.f, 0.f, 0.f};
      acc[i][j] = z;
    }

  const int lrow = tid >> 1;
  const int lcol = (tid & 1) * 16;
  const float* xp = x + (size_t)(m0 + lrow) * I_ + lcol;
  const float* wp = Wi + (size_t)(n0 + lrow) * I_ + lcol;

  for (int k0 = 0; k0 < I_; k0 += PBK) {
    float4 a0 = *(const float4*)(xp + k0);
    float4 a1 = *(const float4*)(xp + k0 + 4);
    float4 a2 = *(const float4*)(xp + k0 + 8);
    float4 a3 = *(const float4*)(xp + k0 + 12);
    float4 b0 = *(const float4*)(wp + k0);
    float4 b1 = *(const float4*)(wp + k0 + 4);
    float4 b2 = *(const float4*)(wp + k0 + 8);
    float4 b3 = *(const float4*)(wp + k0 + 12);
    __syncthreads();
    *(bf16x8*)&As[lrow * PLDA + lcol] = pack8(a0, a1);
    *(bf16x8*)&As[lrow * PLDA + lcol + 8] = pack8(a2, a3);
    *(bf16x8*)&Bs[lrow * PLDA + lcol] = pack8(b0, b1);
    *(bf16x8*)&Bs[lrow * PLDA + lcol + 8] = pack8(b2, b3);
    __syncthreads();

    bf16x8 af[4], bfr[4];
#pragma unroll
    for (int i = 0; i < 4; ++i)
      af[i] = *(const bf16x8*)&As[(wm + i * 16 + lm) * PLDA + lq * 8];
#pragma unroll
    for (int j = 0; j < 4; ++j)
      bfr[j] = *(const bf16x8*)&Bs[(wn + j * 16 + lm) * PLDA + lq * 8];
#pragma unroll
    for (int i = 0; i < 4; ++i)
#pragma unroll
      for (int j = 0; j < 4; ++j)
        acc[i][j] = __builtin_amdgcn_mfma_f32_16x16x32_bf16(af[i], bfr[j],
                                                            acc[i][j], 0, 0, 0);
  }

  const int rb = m0 + wm + lq * 4;
  const int cb = n0 + wn + lm;
#pragma unroll
  for (int j = 0; j < 4; ++j) {
    const int n = cb + j * 16;
    const float bias = bi[n] + bh[n];
#pragma unroll
    for (int i = 0; i < 4; ++i) {
      const int m = rb + i * 16;
#pragma unroll
      for (int r = 0; r < 4; ++r)
        out[(size_t)(m + r) * H_ + n] = acc[i][j][r] + bias;
    }
  }
}

// ---------------------------------------------------------------------------
// Agent-scope (L3-coherent, L2-bypassing) helpers.
// ---------------------------------------------------------------------------
static __device__ __forceinline__ unsigned long long ld_a8(const void* p) {
  return __hip_atomic_load((const unsigned long long*)p, __ATOMIC_RELAXED,
                           __HIP_MEMORY_SCOPE_AGENT);
}
static __device__ __forceinline__ void st_a2(unsigned short* p,
                                             unsigned short v) {
  __hip_atomic_store(p, v, __ATOMIC_RELAXED, __HIP_MEMORY_SCOPE_AGENT);
}
static __device__ __forceinline__ int ld_flag(const int* p) {
  return __hip_atomic_load(p, __ATOMIC_RELAXED, __HIP_MEMORY_SCOPE_AGENT);
}

union frag_u {
  unsigned long long q[2];
  bf16x8 v;
};

// ---------------------------------------------------------------------------
// Kernel 2: persistent recurrence. No LDS in the K-loop: Wh hi+lo B-frags
// live in 256 VGPRs (occupancy is structurally 1 wave/SIMD, so ~512 VGPRs
// are available); h exchanged via two SEPARATE bf16 planes (hi, lo) in exact
// A-frag order so each ld_a8 pair IS a fragment half (zero unpack VALU).
//
// hi-plane layout (shorts): A[b][n], b=wv*16+m, n=kb*32+q*8+j at
//   (kb*4+wv)*512 + q*128 + m*8 + j
// => consumer wave wv, block kb, lane l=q*16+m: 16 B at
//   byte (kb*4+wv)*1024 + lane*16  -- 64 lanes x 16 B fully dense.
// lo plane at +131072 bytes. Plane pair p at planes + p*131072 (shorts).
//
// kb STAGGER (from R5): WG g walks km=(g+i)&31; B-regs are stored rotated
// (Bh[i] <-> km) so register indices stay compile-time constant.
//
// Sync (unchanged from R5): 64 per-WG flags, producer h-stores -> vmcnt(0)
// -> __syncthreads -> tid0 flag[g]=s; consumer lane l polls flag[l], one
// sc1 load/round + s_sleep backoff. flag[g]>=s proves WG g's h_s is at L3
// AND its plane-((s-1)&1) reads retired -> ping-pong safe.
// ---------------------------------------------------------------------------
__global__ __launch_bounds__(256, 1) void rnn_rec(
    const float* __restrict__ Wh, float* __restrict__ out,
    unsigned short* __restrict__ planes, int* __restrict__ flags) {
  const int tid = threadIdx.x;
  const int g = blockIdx.x;
  const int n0 = g * 16;
  const int wv = tid >> 6;   // 0..3
  const int lane = tid & 63;
  const int lm = lane & 15, lq = lane >> 4;
  const int kb0 = g & 31;    // staggered K start

  // --- B-frags (hi+lo) into registers, rotated: Bh[i] holds km=(kb0+i)&31.
  // Lane l needs Wh[n0 + (l&15)][km*32 + (l>>4)*8 + j], j=0..7.
  bf16x8 Bh[32], Bl[32];
  {
    const float* wrow = Wh + (size_t)(n0 + lm) * H_ + lq * 8;
#pragma unroll
    for (int i = 0; i < 32; ++i) {
      const int km = (kb0 + i) & 31;
      float4 w0 = *(const float4*)(wrow + km * 32);
      float4 w1 = *(const float4*)(wrow + km * 32 + 4);
      float wf[8] = {w0.x, w0.y, w0.z, w0.w, w1.x, w1.y, w1.z, w1.w};
      bf16x8 hi, lo;
#pragma unroll
      for (int j = 0; j < 8; ++j) {
        hi[j] = f2bf(wf[j]);
        lo[j] = f2bf(wf[j] - bf2f(hi[j]));
      }
      Bh[i] = hi;
      Bl[i] = lo;
    }
  }

  // --- producer constants: thread owns (b = wv*16 + lq*4 + r, np) ---
  const int np = n0 + lm;
  const int kbp = np >> 5, qp = (np >> 3) & 3, jp = np & 7;
  const int Sbase = (kbp * 4 + wv) * 512 + qp * 128 + lq * 32 + jp;
  // short index for r: Sbase + r*8 (m = lq*4+r -> m*8)

  // --- startup: zero h_0 (pair 0, hi+lo) own slots; flag[g]=0; wait all>=0 ---
#pragma unroll
  for (int r = 0; r < 4; ++r) {
    st_a2(&planes[Sbase + r * 8], 0);
    st_a2(&planes[PSH + Sbase + r * 8], 0);
  }
  asm volatile("s_waitcnt vmcnt(0)" ::: "memory");
  __syncthreads();
  if (tid == 0)
    __hip_atomic_store(&flags[g * FPAD], 0, __ATOMIC_RELAXED,
                       __HIP_MEMORY_SCOPE_AGENT);
  for (;;) {  // 0xAA poison is negative, so >=0 means "flag written"
    const int f = ld_flag(&flags[lane * FPAD]);
    if (__all(f >= 0)) break;
    __builtin_amdgcn_s_sleep(1);
  }

  float* outH = out + (size_t)B_ * T_ * H_;
  const f32x4 z = {0.f, 0.f, 0.f, 0.f};

  for (int s = 1; s <= T_; ++s) {
    const int t = s - 1;
    // prefetch pre values (independent of sync; overlaps the poll)
    size_t oidx[4];
    float pre[4];
#pragma unroll
    for (int r = 0; r < 4; ++r) {
      const int b = wv * 16 + lq * 4 + r;
      oidx[r] = (size_t)b * (T_ * H_) + (size_t)t * H_ + np;
      pre[r] = out[oidx[r]];
    }

    // wait: all 64 WG flags >= s-1; one sc1 load per round + sleep backoff
    const int need = s - 1;
    for (;;) {
      const int f = ld_flag(&flags[lane * FPAD]);
      if (__all(f >= need)) break;
      __builtin_amdgcn_s_sleep(1);
    }

    const char* srcH = (const char*)(planes + (size_t)((s - 1) & 1) * 2 * PSH);
    unsigned short* dstH = planes + (size_t)(s & 1) * 2 * PSH;

    // depth-8 slot pipeline; slot = i&7; per block: 2x8B hi + 2x8B lo.
    // lo plane at byte offset 131072 from hi.
    unsigned long long qh[8][2], ql[8][2];
#pragma unroll
    for (int i = 0; i < 8; ++i) {
      const int km = (kb0 + i) & 31;
      const char* p = srcH + ((size_t)(km * 4 + wv) * 1024) + lane * 16;
      qh[i][0] = ld_a8(p);
      qh[i][1] = ld_a8(p + 8);
      ql[i][0] = ld_a8(p + 131072);
      ql[i][1] = ld_a8(p + 131072 + 8);
    }

    f32x4 c0 = z, c1 = z, c2 = z;
#pragma unroll
    for (int i = 0; i < 32; ++i) {
      const int sl = i & 7;
      frag_u ah, al;
      ah.q[0] = qh[sl][0];
      ah.q[1] = qh[sl][1];
      al.q[0] = ql[sl][0];
      al.q[1] = ql[sl][1];
      c0 = __builtin_amdgcn_mfma_f32_16x16x32_bf16(ah.v, Bh[i], c0, 0, 0, 0);
      c1 = __builtin_amdgcn_mfma_f32_16x16x32_bf16(ah.v, Bl[i], c1, 0, 0, 0);
      c2 = __builtin_amdgcn_mfma_f32_16x16x32_bf16(al.v, Bh[i], c2, 0, 0, 0);
      if (i + 8 < 32) {
        const int kn = (kb0 + i + 8) & 31;
        const char* p = srcH + ((size_t)(kn * 4 + wv) * 1024) + lane * 16;
        qh[sl][0] = ld_a8(p);
        qh[sl][1] = ld_a8(p + 8);
        ql[sl][0] = ld_a8(p + 131072);
        ql[sl][1] = ld_a8(p + 131072 + 8);
      }
    }
    const f32x4 rs = c0 + c1 + c2;

    // epilogue: h-plane stores FIRST, per-wave drain, WG-convergence, signal
    float v[4];
#pragma unroll
    for (int r = 0; r < 4; ++r) {
      float vv = pre[r] + rs[r];
      vv = vv > 0.f ? vv : 0.f;
      v[r] = vv;
      const short hv = f2bf(vv);
      const short lv = f2bf(vv - bf2f(hv));
      st_a2(&dstH[Sbase + r * 8], (unsigned short)hv);
      st_a2(&dstH[PSH + Sbase + r * 8], (unsigned short)lv);
    }
    asm volatile("s_waitcnt vmcnt(0)" ::: "memory");  // this wave's h at L3
    __syncthreads();                                  // all 4 waves drained
    if (tid == 0)
      __hip_atomic_store(&flags[g * FPAD], s, __ATOMIC_RELAXED,
                         __HIP_MEMORY_SCOPE_AGENT);
    // out writes off the critical chain (WG-private, L2-cached)
#pragma unroll
    for (int r = 0; r < 4; ++r) {
      out[oidx[r]] = v[r];
      if (s == T_) outH[(size_t)(wv * 16 + lq * 4 + r) * H_ + np] = v[r];
    }
  }
}

// ---------------------------------------------------------------------------
extern "C" void kernel_launch(void* const* d_in, const int* in_sizes, int n_in,
                              void* d_out, int out_size, void* d_ws,
                              size_t ws_size, hipStream_t stream) {
  const float* x = (const float*)d_in[0];   // [B,T,I]
  const float* Wi = (const float*)d_in[1];  // [H,I]
  const float* bi = (const float*)d_in[2];  // [H]
  const float* Wh = (const float*)d_in[3];  // [H,H]
  const float* bh = (const float*)d_in[4];  // [H]
  float* out = (float*)d_out;

  int* flags = (int*)d_ws;  // 64 x 64 B = 4 KB
  unsigned short* planes =
      (unsigned short*)((char*)d_ws + G_ * FPAD * 4);  // 2 pairs x 256 KB

  proj_gemm<<<2048, 256, 0, stream>>>(x, Wi, bi, bh, out);
  rnn_rec<<<G_, 256, 0, stream>>>(Wh, out, planes, flags);
}